// Round 1
// baseline (174.048 us; speedup 1.0000x reference)
//
#include <hip/hip_runtime.h>
#include <math.h>

// Problem: loss = 1 - corr(I_model, I_exp), where I_model comes from three
// 4096x4096 linear solves. The matrix is (6c+eps_i)I - c*S with S a random
// 6-out-neighbour adjacency (duplicates collapse via .set semantics).
// Algorithm: Jacobi iteration (bulk spectral radius ~0.41) + vector Aitken
// extrapolation of the single slow Perron mode (mu ~ 1-6e-4), entirely in LDS.

#define NN    4096
#define DEGN  6
#define NC    5
#define TPB   1024
#define RPT   4            // rows per thread: 4096/1024
#define PADSLOT NN         // dummy LDS slot (always 0) for deduped neighbours
#define XDIM (NN + 8)

__device__ __forceinline__ double wave_reduce_d(double v) {
  #pragma unroll
  for (int off = 32; off > 0; off >>= 1) v += __shfl_down(v, off, 64);
  return v;
}

__global__ __launch_bounds__(TPB, 1)
void solve_kernel(const float* __restrict__ th_a,
                  const float* __restrict__ th_b,
                  const float* __restrict__ th_c,
                  const float* __restrict__ cd,     // (4096,5) row-major
                  const int*   __restrict__ nbrg,   // (4096,6) row-major
                  double* __restrict__ wsI)         // 3 x 25 model values
{
  __shared__ float  xb[2][XDIM];
  __shared__ double red[96];

  const float* th = (blockIdx.x == 0) ? th_a : (blockIdx.x == 1) ? th_b : th_c;
  const int tid  = threadIdx.x;
  const int lane = tid & 63;
  const int wid  = tid >> 6;

  // ---- constants (double-precision folds) ----
  const double AREA_D = 0.8660254037844386 * 8.45e-5 * 8.45e-5;   // sqrt(3)/2 * L_C^2
  const double LR_D   = 0.5773502691896258;                        // 1/sqrt(3)
  const double BS_D   = 1e12;                                      // B_SCALE / A_SCALE

  // ---- theta ----
  const float D   = th[0];
  const float lam = th[1];
  const float K   = th[7];
  float rho[NC], rec[NC];
  #pragma unroll
  for (int m = 0; m < NC; ++m) { rho[m] = th[2 + m]; rec[m] = th[8 + m]; }
  const float c = (float)((double)D * LR_D);

  // ---- per-row setup (4 rows per thread, strided by 1024) ----
  int   nb[RPT][DEGN];
  float rinvd[RPT], cinvd[RPT], invsr[RPT], cdv[RPT][NC];

  #pragma unroll
  for (int j = 0; j < RPT; ++j) {
    const int i = tid + j * TPB;
    float srho = 0.f, srec = 0.f;
    #pragma unroll
    for (int m = 0; m < NC; ++m) {
      const float v = cd[i * NC + m];
      cdv[j][m] = v;
      srho += v * rho[m];
      srec += v * rec[m];
    }
    const double diag = 6.0 * (double)c + AREA_D * ((double)lam + (double)K * (double)srec);
    const double rr   = AREA_D * BS_D * (double)srho;   // b / A_SCALE
    rinvd[j] = (float)(rr / diag);
    cinvd[j] = (float)((double)c / diag);
    invsr[j] = 1.0f / srho;
    #pragma unroll
    for (int t = 0; t < DEGN; ++t) nb[j][t] = nbrg[i * DEGN + t];
    // .set semantics: duplicate neighbour indices collapse to a single -c entry
    #pragma unroll
    for (int t = 1; t < DEGN; ++t) {
      #pragma unroll
      for (int u = 0; u < t; ++u) {
        if (nb[j][t] == nb[j][u]) nb[j][t] = PADSLOT;
      }
    }
  }

  // ---- init x0 = D^{-1} b ----
  if (tid < 8) { xb[0][NN + tid] = 0.f; xb[1][NN + tid] = 0.f; }
  float xc[RPT], xp[RPT], xpp[RPT];
  #pragma unroll
  for (int j = 0; j < RPT; ++j) {
    xc[j] = rinvd[j]; xp[j] = xc[j]; xpp[j] = xc[j];
    xb[0][tid + j * TPB] = xc[j];
  }
  __syncthreads();

  // ---- Jacobi + Aitken rounds ----
  int cur = 0;
  for (int rd = 0; rd < 3; ++rd) {
    const int iters = (rd == 0) ? 40 : 16;
    for (int it = 0; it < iters; ++it) {
      float xn[RPT];
      #pragma unroll
      for (int j = 0; j < RPT; ++j) {
        float s = 0.f;
        #pragma unroll
        for (int t = 0; t < DEGN; ++t) s += xb[cur][nb[j][t]];
        xn[j] = rinvd[j] + cinvd[j] * s;
      }
      #pragma unroll
      for (int j = 0; j < RPT; ++j) xb[cur ^ 1][tid + j * TPB] = xn[j];
      __syncthreads();
      #pragma unroll
      for (int j = 0; j < RPT; ++j) { xpp[j] = xp[j]; xp[j] = xc[j]; xc[j] = xn[j]; }
      cur ^= 1;
    }

    // Aitken: x* = x_{k+1} + mu/(1-mu) * d2,  mu = <d1,d2>/<d1,d1>
    double d11 = 0.0, d12 = 0.0, dxx = 0.0;
    #pragma unroll
    for (int j = 0; j < RPT; ++j) {
      const double d1 = (double)xp[j] - (double)xpp[j];
      const double d2 = (double)xc[j] - (double)xp[j];
      d11 += d1 * d1; d12 += d1 * d2; dxx += (double)xc[j] * (double)xc[j];
    }
    d11 = wave_reduce_d(d11); d12 = wave_reduce_d(d12); dxx = wave_reduce_d(dxx);
    if (lane == 0) { red[wid] = d11; red[16 + wid] = d12; red[32 + wid] = dxx; }
    __syncthreads();
    if (tid == 0) {
      double a = 0.0, b = 0.0, x2 = 0.0;
      for (int w = 0; w < 16; ++w) { a += red[w]; b += red[16 + w]; x2 += red[32 + w]; }
      double f = 0.0;
      if (a > 1e-12 * x2) {                 // skip if at fp32 quantization floor
        double mu = b / a;
        if (mu > -0.5) {
          if (mu > 0.9999) mu = 0.9999;     // cap amplification at 1e4
          f = mu / (1.0 - mu);
        }
      }
      red[90] = f;
    }
    __syncthreads();
    const float f = (float)red[90];
    #pragma unroll
    for (int j = 0; j < RPT; ++j) {
      xc[j] = xc[j] + f * (xc[j] - xp[j]);
      xb[cur][tid + j * TPB] = xc[j];
      xp[j] = xc[j]; xpp[j] = xc[j];
    }
    __syncthreads();
  }

  // ---- epilogue: s_b = sum_i g_i * cd[i,b]*rho_b / (cd[i,:]@rho) ----
  double acc[NC] = {0, 0, 0, 0, 0};
  #pragma unroll
  for (int j = 0; j < RPT; ++j) {
    const double gs = (double)xc[j] * (double)invsr[j];
    #pragma unroll
    for (int b = 0; b < NC; ++b) acc[b] += gs * (double)cdv[j][b];
  }
  #pragma unroll
  for (int b = 0; b < NC; ++b) acc[b] = wave_reduce_d(acc[b]);
  __syncthreads();                       // red[] reuse
  if (lane == 0) {
    #pragma unroll
    for (int b = 0; b < NC; ++b) red[b * 16 + wid] = acc[b];
  }
  __syncthreads();
  if (tid == 0) {
    double s[NC];
    for (int b = 0; b < NC; ++b) {
      double t = 0.0;
      for (int w = 0; w < 16; ++w) t += red[b * 16 + w];
      s[b] = t * (double)rho[b];
    }
    // I[a][b] = K * rec[a] * s[b] / N  (row-major ravel matches jnp)
    for (int a = 0; a < NC; ++a)
      for (int b = 0; b < NC; ++b)
        wsI[blockIdx.x * 25 + a * NC + b] = (double)K * (double)rec[a] * s[b] / (double)NN;
  }
}

__global__ __launch_bounds__(64)
void loss_kernel(const double* __restrict__ wsI,
                 const float*  __restrict__ iexp,
                 float* __restrict__ out)
{
  const int lane = threadIdx.x;
  double sm = 0, sd = 0, smm = 0, sdd = 0, smd = 0;
  for (int i = lane; i < 75; i += 64) {
    const double m = wsI[i];
    const double d = (double)iexp[i];
    sm += m; sd += d; smm += m * m; sdd += d * d; smd += m * d;
  }
  sm = wave_reduce_d(sm); sd = wave_reduce_d(sd);
  smm = wave_reduce_d(smm); sdd = wave_reduce_d(sdd); smd = wave_reduce_d(smd);
  if (lane == 0) {
    const double n = 75.0;
    const double mm = sm / n, md = sd / n;
    const double cov = smd / n - mm * md;
    const double vm = smm / n - mm * mm;
    const double vd = sdd / n - md * md;
    out[0] = (float)(1.0 - cov / (sqrt(vm) * sqrt(vd)));
  }
}

extern "C" void kernel_launch(void* const* d_in, const int* in_sizes, int n_in,
                              void* d_out, int out_size, void* d_ws, size_t ws_size,
                              hipStream_t stream) {
  const float* th1  = (const float*)d_in[0];
  const float* th2  = (const float*)d_in[1];
  const float* th3  = (const float*)d_in[2];
  const float* cd   = (const float*)d_in[3];
  const float* iexp = (const float*)d_in[4];
  const int*   nbr  = (const int*)d_in[5];
  double* wsI = (double*)d_ws;

  solve_kernel<<<3, TPB, 0, stream>>>(th1, th2, th3, cd, nbr, wsI);
  loss_kernel<<<1, 64, 0, stream>>>(wsI, iexp, (float*)d_out);
}

// Round 2
// 121.719 us; speedup vs baseline: 1.4299x; 1.4299x over previous
//
#include <hip/hip_runtime.h>
#include <math.h>

// loss = 1 - corr(I_model, I_exp); I_model from three 4096x4096 solves with
// A = (6c+eps_i)I - c*S, S = random 6-out adjacency (dups collapse via .set).
// Jacobi (bulk radius ~0.41) + guarded vector Aitken for the Perron mode
// (mu ~ 1-6e-4), whole state in LDS. Loss fused via last-block pattern.
//
// Round-2 changes vs round 1 (which passed, absmax 0.0, solve=113us):
//  - sweeps 72 -> 30 (20+A, 6+A, 4+A): bulk at 0.41^20~2e-8; residual Aitken
//    error is along the Perron vector == near-pure scale of g == invisible to
//    the correlation loss (solution is Perron-dominated, bulk/Perron ~1e-3).
//  - loss computed by the last solve block (flag + threadfence + atomicAdd),
//    removing the second kernel launch and its gap.

#define NN    4096
#define DEGN  6
#define NC    5
#define TPB   1024
#define RPT   4            // rows per thread: 4096/1024
#define PADSLOT NN         // dummy LDS slot (always 0) for deduped neighbours
#define XDIM (NN + 8)

__device__ __forceinline__ double wave_reduce_d(double v) {
  #pragma unroll
  for (int off = 32; off > 0; off >>= 1) v += __shfl_down(v, off, 64);
  return v;
}

__global__ __launch_bounds__(TPB, 1)
void solve_kernel(const float* __restrict__ th_a,
                  const float* __restrict__ th_b,
                  const float* __restrict__ th_c,
                  const float* __restrict__ cd,     // (4096,5) row-major
                  const int*   __restrict__ nbrg,   // (4096,6) row-major
                  const float* __restrict__ iexp,   // (75,)
                  int*    flag,                      // d_ws+0, memset to 0
                  double* wsI,                       // d_ws+64: 3 x 25 doubles
                  float*  out)
{
  __shared__ float  xb[2][XDIM];
  __shared__ double red[96];
  __shared__ int    s_last;

  const float* th = (blockIdx.x == 0) ? th_a : (blockIdx.x == 1) ? th_b : th_c;
  const int tid  = threadIdx.x;
  const int lane = tid & 63;
  const int wid  = tid >> 6;

  const double AREA_D = 0.8660254037844386 * 8.45e-5 * 8.45e-5;   // sqrt(3)/2*L_C^2
  const double LR_D   = 0.5773502691896258;                        // 1/sqrt(3)
  const double BS_D   = 1e12;                                      // B_SCALE/A_SCALE

  const float D   = th[0];
  const float lam = th[1];
  const float K   = th[7];
  float rho[NC], rec[NC];
  #pragma unroll
  for (int m = 0; m < NC; ++m) { rho[m] = th[2 + m]; rec[m] = th[8 + m]; }
  const float c = (float)((double)D * LR_D);

  // ---- per-row setup ----
  int   nb[RPT][DEGN];
  float rinvd[RPT], cinvd[RPT], invsr[RPT], cdv[RPT][NC];

  #pragma unroll
  for (int j = 0; j < RPT; ++j) {
    const int i = tid + j * TPB;
    float srho = 0.f, srec = 0.f;
    #pragma unroll
    for (int m = 0; m < NC; ++m) {
      const float v = cd[i * NC + m];
      cdv[j][m] = v;
      srho += v * rho[m];
      srec += v * rec[m];
    }
    const double diag = 6.0 * (double)c + AREA_D * ((double)lam + (double)K * (double)srec);
    const double rr   = AREA_D * BS_D * (double)srho;   // b / A_SCALE
    rinvd[j] = (float)(rr / diag);
    cinvd[j] = (float)((double)c / diag);
    invsr[j] = 1.0f / srho;
    #pragma unroll
    for (int t = 0; t < DEGN; ++t) nb[j][t] = nbrg[i * DEGN + t];
    // .set semantics: duplicate neighbour indices collapse to one -c entry
    #pragma unroll
    for (int t = 1; t < DEGN; ++t) {
      #pragma unroll
      for (int u = 0; u < t; ++u) {
        if (nb[j][t] == nb[j][u]) nb[j][t] = PADSLOT;
      }
    }
  }

  // ---- init x0 = D^{-1} b ----
  if (tid < 8) { xb[0][NN + tid] = 0.f; xb[1][NN + tid] = 0.f; }
  float xc[RPT], xp[RPT], xpp[RPT];
  #pragma unroll
  for (int j = 0; j < RPT; ++j) {
    xc[j] = rinvd[j]; xp[j] = xc[j]; xpp[j] = xc[j];
    xb[0][tid + j * TPB] = xc[j];
  }
  __syncthreads();

  // ---- Jacobi + guarded Aitken rounds: 20+A, 6+A, 4+A ----
  int cur = 0;
  for (int rd = 0; rd < 3; ++rd) {
    const int iters = (rd == 0) ? 20 : (rd == 1) ? 6 : 4;
    for (int it = 0; it < iters; ++it) {
      float xn[RPT];
      #pragma unroll
      for (int j = 0; j < RPT; ++j) {
        float s = 0.f;
        #pragma unroll
        for (int t = 0; t < DEGN; ++t) s += xb[cur][nb[j][t]];
        xn[j] = rinvd[j] + cinvd[j] * s;
      }
      #pragma unroll
      for (int j = 0; j < RPT; ++j) xb[cur ^ 1][tid + j * TPB] = xn[j];
      __syncthreads();
      #pragma unroll
      for (int j = 0; j < RPT; ++j) { xpp[j] = xp[j]; xp[j] = xc[j]; xc[j] = xn[j]; }
      cur ^= 1;
    }

    // Aitken: x* = x_{k+1} + mu/(1-mu)*d2,  mu = <d1,d2>/<d1,d1>
    double d11 = 0.0, d12 = 0.0, dxx = 0.0;
    #pragma unroll
    for (int j = 0; j < RPT; ++j) {
      const double d1 = (double)xp[j] - (double)xpp[j];
      const double d2 = (double)xc[j] - (double)xp[j];
      d11 += d1 * d1; d12 += d1 * d2; dxx += (double)xc[j] * (double)xc[j];
    }
    d11 = wave_reduce_d(d11); d12 = wave_reduce_d(d12); dxx = wave_reduce_d(dxx);
    if (lane == 0) { red[wid] = d11; red[16 + wid] = d12; red[32 + wid] = dxx; }
    __syncthreads();
    if (tid == 0) {
      double a = 0.0, b = 0.0, x2 = 0.0;
      for (int w = 0; w < 16; ++w) { a += red[w]; b += red[16 + w]; x2 += red[32 + w]; }
      double f = 0.0;
      if (a > 1e-12 * x2) {                 // skip at fp32 quantization floor
        double mu = b / a;
        if (mu > -0.5) {
          if (mu > 0.9999) mu = 0.9999;     // cap amplification at 1e4
          f = mu / (1.0 - mu);
        }
      }
      red[90] = f;
    }
    __syncthreads();
    const float f = (float)red[90];
    #pragma unroll
    for (int j = 0; j < RPT; ++j) {
      xc[j] = xc[j] + f * (xc[j] - xp[j]);
      xb[cur][tid + j * TPB] = xc[j];
      xp[j] = xc[j]; xpp[j] = xc[j];
    }
    __syncthreads();
  }

  // ---- epilogue: s_b = sum_i g_i * cd[i,b] / (cd[i,:]@rho) ----
  double acc[NC] = {0, 0, 0, 0, 0};
  #pragma unroll
  for (int j = 0; j < RPT; ++j) {
    const double gs = (double)xc[j] * (double)invsr[j];
    #pragma unroll
    for (int b = 0; b < NC; ++b) acc[b] += gs * (double)cdv[j][b];
  }
  #pragma unroll
  for (int b = 0; b < NC; ++b) acc[b] = wave_reduce_d(acc[b]);
  __syncthreads();
  if (lane == 0) {
    #pragma unroll
    for (int b = 0; b < NC; ++b) red[b * 16 + wid] = acc[b];
  }
  __syncthreads();
  if (tid == 0) {
    double s[NC];
    for (int b = 0; b < NC; ++b) {
      double t = 0.0;
      for (int w = 0; w < 16; ++w) t += red[b * 16 + w];
      s[b] = t * (double)rho[b];
    }
    // I[a][b] = K*rec[a]*s[b]/N, row-major ravel
    for (int a = 0; a < NC; ++a)
      for (int b = 0; b < NC; ++b)
        wsI[blockIdx.x * 25 + a * NC + b] = (double)K * (double)rec[a] * s[b] / (double)NN;
    __threadfence();                         // publish before arrival (device scope)
    s_last = atomicAdd(flag, 1);             // device-scope by default
  }
  __syncthreads();

  // ---- last block computes the loss ----
  if (s_last == 2 && tid < 64) {
    __threadfence();                         // acquire side
    const volatile double* vI = (const volatile double*)wsI;
    double sm = 0, sd = 0, smm = 0, sdd = 0, smd = 0;
    for (int i = lane; i < 75; i += 64) {
      const double m = vI[i];
      const double d = (double)iexp[i];
      sm += m; sd += d; smm += m * m; sdd += d * d; smd += m * d;
    }
    sm = wave_reduce_d(sm); sd = wave_reduce_d(sd);
    smm = wave_reduce_d(smm); sdd = wave_reduce_d(sdd); smd = wave_reduce_d(smd);
    if (lane == 0) {
      const double n = 75.0;
      const double mm = sm / n, md = sd / n;
      const double cov = smd / n - mm * md;
      const double vm = smm / n - mm * mm;
      const double vd = sdd / n - md * md;
      out[0] = (float)(1.0 - cov / (sqrt(vm) * sqrt(vd)));
    }
  }
}

extern "C" void kernel_launch(void* const* d_in, const int* in_sizes, int n_in,
                              void* d_out, int out_size, void* d_ws, size_t ws_size,
                              hipStream_t stream) {
  const float* th1  = (const float*)d_in[0];
  const float* th2  = (const float*)d_in[1];
  const float* th3  = (const float*)d_in[2];
  const float* cd   = (const float*)d_in[3];
  const float* iexp = (const float*)d_in[4];
  const int*   nbr  = (const int*)d_in[5];

  int*    flag = (int*)d_ws;                          // offset 0
  double* wsI  = (double*)((char*)d_ws + 64);         // 75 doubles

  hipMemsetAsync(d_ws, 0, 64, stream);                // capturable memset node
  solve_kernel<<<3, TPB, 0, stream>>>(th1, th2, th3, cd, nbr, iexp,
                                      flag, wsI, (float*)d_out);
}

// Round 3
// 98.199 us; speedup vs baseline: 1.7724x; 1.2395x over previous
//
#include <hip/hip_runtime.h>
#include <math.h>

// loss = 1 - corr(I_model, I_exp); I_model from three 4096x4096 solves with
// A = (6c+eps_i)I - c*S, S = random 6-out adjacency (dups collapse via .set).
// Jacobi (bulk radius ~0.41, circular-law disk -> power iteration is the
// optimal bulk polynomial) + guarded vector Aitken for the lone Perron
// outlier (mu ~ 1-6e-4). Whole state in LDS; loss fused via last-block.
//
// Round-3 change vs round 2 (passed, absmax 0.0, solve=59us, total=122us):
//  - sweeps 30 -> 16 (12+Aitken, 4+Aitken). Error model: Perron:bulk in the
//    difference vectors ~ 0.69*2.43^k -> mu-hat good to ~3e-5 at k=12;
//    post-Aitken rel err ~3e-5, second round -> ~1e-6. Need only ~1e-2.
//  - total fixed overhead outside the kernel (~62us) is launch/graph cost,
//    invariant across rounds; kernel body is the only remaining lever.

#define NN    4096
#define DEGN  6
#define NC    5
#define TPB   1024
#define RPT   4            // rows per thread: 4096/1024
#define PADSLOT NN         // dummy LDS slot (always 0) for deduped neighbours
#define XDIM (NN + 8)

__device__ __forceinline__ double wave_reduce_d(double v) {
  #pragma unroll
  for (int off = 32; off > 0; off >>= 1) v += __shfl_down(v, off, 64);
  return v;
}

__global__ __launch_bounds__(TPB, 1)
void solve_kernel(const float* __restrict__ th_a,
                  const float* __restrict__ th_b,
                  const float* __restrict__ th_c,
                  const float* __restrict__ cd,     // (4096,5) row-major
                  const int*   __restrict__ nbrg,   // (4096,6) row-major
                  const float* __restrict__ iexp,   // (75,)
                  int*    flag,                      // d_ws+0, memset to 0
                  double* wsI,                       // d_ws+64: 3 x 25 doubles
                  float*  out)
{
  __shared__ float  xb[2][XDIM];
  __shared__ double red[96];
  __shared__ int    s_last;

  const float* th = (blockIdx.x == 0) ? th_a : (blockIdx.x == 1) ? th_b : th_c;
  const int tid  = threadIdx.x;
  const int lane = tid & 63;
  const int wid  = tid >> 6;

  const double AREA_D = 0.8660254037844386 * 8.45e-5 * 8.45e-5;   // sqrt(3)/2*L_C^2
  const double LR_D   = 0.5773502691896258;                        // 1/sqrt(3)
  const double BS_D   = 1e12;                                      // B_SCALE/A_SCALE

  const float D   = th[0];
  const float lam = th[1];
  const float K   = th[7];
  float rho[NC], rec[NC];
  #pragma unroll
  for (int m = 0; m < NC; ++m) { rho[m] = th[2 + m]; rec[m] = th[8 + m]; }
  const float c = (float)((double)D * LR_D);

  // ---- per-row setup ----
  int   nb[RPT][DEGN];
  float rinvd[RPT], cinvd[RPT], invsr[RPT], cdv[RPT][NC];

  #pragma unroll
  for (int j = 0; j < RPT; ++j) {
    const int i = tid + j * TPB;
    float srho = 0.f, srec = 0.f;
    #pragma unroll
    for (int m = 0; m < NC; ++m) {
      const float v = cd[i * NC + m];
      cdv[j][m] = v;
      srho += v * rho[m];
      srec += v * rec[m];
    }
    const double diag = 6.0 * (double)c + AREA_D * ((double)lam + (double)K * (double)srec);
    const double rr   = AREA_D * BS_D * (double)srho;   // b / A_SCALE
    rinvd[j] = (float)(rr / diag);
    cinvd[j] = (float)((double)c / diag);
    invsr[j] = 1.0f / srho;
    #pragma unroll
    for (int t = 0; t < DEGN; ++t) nb[j][t] = nbrg[i * DEGN + t];
    // .set semantics: duplicate neighbour indices collapse to one -c entry
    #pragma unroll
    for (int t = 1; t < DEGN; ++t) {
      #pragma unroll
      for (int u = 0; u < t; ++u) {
        if (nb[j][t] == nb[j][u]) nb[j][t] = PADSLOT;
      }
    }
  }

  // ---- init x0 = D^{-1} b ----
  if (tid < 8) { xb[0][NN + tid] = 0.f; xb[1][NN + tid] = 0.f; }
  float xc[RPT], xp[RPT], xpp[RPT];
  #pragma unroll
  for (int j = 0; j < RPT; ++j) {
    xc[j] = rinvd[j]; xp[j] = xc[j]; xpp[j] = xc[j];
    xb[0][tid + j * TPB] = xc[j];
  }
  __syncthreads();

  // ---- Jacobi + guarded Aitken rounds: 12+A, 4+A ----
  int cur = 0;
  for (int rd = 0; rd < 2; ++rd) {
    const int iters = (rd == 0) ? 12 : 4;
    for (int it = 0; it < iters; ++it) {
      float xn[RPT];
      #pragma unroll
      for (int j = 0; j < RPT; ++j) {
        float s = 0.f;
        #pragma unroll
        for (int t = 0; t < DEGN; ++t) s += xb[cur][nb[j][t]];
        xn[j] = rinvd[j] + cinvd[j] * s;
      }
      #pragma unroll
      for (int j = 0; j < RPT; ++j) xb[cur ^ 1][tid + j * TPB] = xn[j];
      __syncthreads();
      #pragma unroll
      for (int j = 0; j < RPT; ++j) { xpp[j] = xp[j]; xp[j] = xc[j]; xc[j] = xn[j]; }
      cur ^= 1;
    }

    // Aitken: x* = x_{k+1} + mu/(1-mu)*d2,  mu = <d1,d2>/<d1,d1>
    double d11 = 0.0, d12 = 0.0, dxx = 0.0;
    #pragma unroll
    for (int j = 0; j < RPT; ++j) {
      const double d1 = (double)xp[j] - (double)xpp[j];
      const double d2 = (double)xc[j] - (double)xp[j];
      d11 += d1 * d1; d12 += d1 * d2; dxx += (double)xc[j] * (double)xc[j];
    }
    d11 = wave_reduce_d(d11); d12 = wave_reduce_d(d12); dxx = wave_reduce_d(dxx);
    if (lane == 0) { red[wid] = d11; red[16 + wid] = d12; red[32 + wid] = dxx; }
    __syncthreads();
    if (tid == 0) {
      double a = 0.0, b = 0.0, x2 = 0.0;
      for (int w = 0; w < 16; ++w) { a += red[w]; b += red[16 + w]; x2 += red[32 + w]; }
      double f = 0.0;
      if (a > 1e-12 * x2) {                 // skip at fp32 quantization floor
        double mu = b / a;
        if (mu > -0.5) {
          if (mu > 0.9999) mu = 0.9999;     // cap amplification at 1e4
          f = mu / (1.0 - mu);
        }
      }
      red[90] = f;
    }
    __syncthreads();
    const float f = (float)red[90];
    #pragma unroll
    for (int j = 0; j < RPT; ++j) {
      xc[j] = xc[j] + f * (xc[j] - xp[j]);
      xb[cur][tid + j * TPB] = xc[j];
      xp[j] = xc[j]; xpp[j] = xc[j];
    }
    __syncthreads();
  }

  // ---- epilogue: s_b = sum_i g_i * cd[i,b] / (cd[i,:]@rho) ----
  double acc[NC] = {0, 0, 0, 0, 0};
  #pragma unroll
  for (int j = 0; j < RPT; ++j) {
    const double gs = (double)xc[j] * (double)invsr[j];
    #pragma unroll
    for (int b = 0; b < NC; ++b) acc[b] += gs * (double)cdv[j][b];
  }
  #pragma unroll
  for (int b = 0; b < NC; ++b) acc[b] = wave_reduce_d(acc[b]);
  __syncthreads();
  if (lane == 0) {
    #pragma unroll
    for (int b = 0; b < NC; ++b) red[b * 16 + wid] = acc[b];
  }
  __syncthreads();
  if (tid == 0) {
    double s[NC];
    for (int b = 0; b < NC; ++b) {
      double t = 0.0;
      for (int w = 0; w < 16; ++w) t += red[b * 16 + w];
      s[b] = t * (double)rho[b];
    }
    // I[a][b] = K*rec[a]*s[b]/N, row-major ravel
    for (int a = 0; a < NC; ++a)
      for (int b = 0; b < NC; ++b)
        wsI[blockIdx.x * 25 + a * NC + b] = (double)K * (double)rec[a] * s[b] / (double)NN;
    __threadfence();                         // publish before arrival (device scope)
    s_last = atomicAdd(flag, 1);             // device-scope by default
  }
  __syncthreads();

  // ---- last block computes the loss ----
  if (s_last == 2 && tid < 64) {
    __threadfence();                         // acquire side
    const volatile double* vI = (const volatile double*)wsI;
    double sm = 0, sd = 0, smm = 0, sdd = 0, smd = 0;
    for (int i = lane; i < 75; i += 64) {
      const double m = vI[i];
      const double d = (double)iexp[i];
      sm += m; sd += d; smm += m * m; sdd += d * d; smd += m * d;
    }
    sm = wave_reduce_d(sm); sd = wave_reduce_d(sd);
    smm = wave_reduce_d(smm); sdd = wave_reduce_d(sdd); smd = wave_reduce_d(smd);
    if (lane == 0) {
      const double n = 75.0;
      const double mm = sm / n, md = sd / n;
      const double cov = smd / n - mm * md;
      const double vm = smm / n - mm * mm;
      const double vd = sdd / n - md * md;
      out[0] = (float)(1.0 - cov / (sqrt(vm) * sqrt(vd)));
    }
  }
}

extern "C" void kernel_launch(void* const* d_in, const int* in_sizes, int n_in,
                              void* d_out, int out_size, void* d_ws, size_t ws_size,
                              hipStream_t stream) {
  const float* th1  = (const float*)d_in[0];
  const float* th2  = (const float*)d_in[1];
  const float* th3  = (const float*)d_in[2];
  const float* cd   = (const float*)d_in[3];
  const float* iexp = (const float*)d_in[4];
  const int*   nbr  = (const int*)d_in[5];

  int*    flag = (int*)d_ws;                          // offset 0
  double* wsI  = (double*)((char*)d_ws + 64);         // 75 doubles

  hipMemsetAsync(d_ws, 0, 64, stream);                // capturable memset node
  solve_kernel<<<3, TPB, 0, stream>>>(th1, th2, th3, cd, nbr, iexp,
                                      flag, wsI, (float*)d_out);
}

// Round 4
// 90.284 us; speedup vs baseline: 1.9278x; 1.0877x over previous
//
#include <hip/hip_runtime.h>
#include <math.h>

// loss = 1 - corr(I_model, I_exp); I_model from three 4096x4096 solves with
// A = (6c+eps_i)I - c*S, S = random 6-out adjacency (dups collapse via .set).
// Jacobi (bulk radius ~0.41, circular-law disk) + guarded vector Aitken for
// the lone Perron outlier (mu ~ 1-6e-4). Whole state in LDS.
//
// Round-4 changes vs round 3 (passed, absmax 0.0, total=98.2us):
//  - sweeps 16 -> 11 (8+Aitken, 3+Aitken). Error model: solution is Perron-
//    dominated (amp ~1600), so Perron-direction error == near-pure scale of
//    I_model == invisible to the correlation loss (f >= -1/3 so no sign
//    flip). Only bulk SHAPE error matters; tolerance 0.41^k/1600 < 1e-2 is
//    trivially met; worst-case bad-mu-hat contamination ~3e-3 is then cut
//    by the +3 sweeps and second Aitken. ~10x margin vs threshold 2.08e-2.
//  - memset node removed: magic-token completion (release/acquire, agent
//    scope) replaces the atomicAdd counter; block 0's wave 0 polls tokens
//    and computes the loss. One fewer serialized dispatch in the graph.
//  - remaining time is dominated by harness-side stream work (268MB d_ws
//    re-poison at ~39us @85% HBM peak + d_in restores + graph launch),
//    which is outside kernel control.

#define NN    4096
#define DEGN  6
#define NC    5
#define TPB   1024
#define RPT   4            // rows per thread: 4096/1024
#define PADSLOT NN         // dummy LDS slot (always 0) for deduped neighbours
#define XDIM (NN + 8)
#define TOK_MAGIC 0x7F3A9C51

__device__ __forceinline__ double wave_reduce_d(double v) {
  #pragma unroll
  for (int off = 32; off > 0; off >>= 1) v += __shfl_down(v, off, 64);
  return v;
}

__global__ __launch_bounds__(TPB, 1)
void solve_kernel(const float* __restrict__ th_a,
                  const float* __restrict__ th_b,
                  const float* __restrict__ th_c,
                  const float* __restrict__ cd,     // (4096,5) row-major
                  const int*   __restrict__ nbrg,   // (4096,6) row-major
                  const float* __restrict__ iexp,   // (75,)
                  int*    tok,                       // d_ws+0: 3 tokens
                  double* wsI,                       // d_ws+64: 3 x 25 doubles
                  float*  out)
{
  __shared__ float  xb[2][XDIM];
  __shared__ double red[96];

  const float* th = (blockIdx.x == 0) ? th_a : (blockIdx.x == 1) ? th_b : th_c;
  const int tid  = threadIdx.x;
  const int lane = tid & 63;
  const int wid  = tid >> 6;

  const double AREA_D = 0.8660254037844386 * 8.45e-5 * 8.45e-5;   // sqrt(3)/2*L_C^2
  const double LR_D   = 0.5773502691896258;                        // 1/sqrt(3)
  const double BS_D   = 1e12;                                      // B_SCALE/A_SCALE

  const float D   = th[0];
  const float lam = th[1];
  const float K   = th[7];
  float rho[NC], rec[NC];
  #pragma unroll
  for (int m = 0; m < NC; ++m) { rho[m] = th[2 + m]; rec[m] = th[8 + m]; }
  const float c = (float)((double)D * LR_D);

  // ---- per-row setup ----
  int   nb[RPT][DEGN];
  float rinvd[RPT], cinvd[RPT], invsr[RPT], cdv[RPT][NC];

  #pragma unroll
  for (int j = 0; j < RPT; ++j) {
    const int i = tid + j * TPB;
    float srho = 0.f, srec = 0.f;
    #pragma unroll
    for (int m = 0; m < NC; ++m) {
      const float v = cd[i * NC + m];
      cdv[j][m] = v;
      srho += v * rho[m];
      srec += v * rec[m];
    }
    const double diag = 6.0 * (double)c + AREA_D * ((double)lam + (double)K * (double)srec);
    const double rr   = AREA_D * BS_D * (double)srho;   // b / A_SCALE
    rinvd[j] = (float)(rr / diag);
    cinvd[j] = (float)((double)c / diag);
    invsr[j] = 1.0f / srho;
    #pragma unroll
    for (int t = 0; t < DEGN; ++t) nb[j][t] = nbrg[i * DEGN + t];
    // .set semantics: duplicate neighbour indices collapse to one -c entry
    #pragma unroll
    for (int t = 1; t < DEGN; ++t) {
      #pragma unroll
      for (int u = 0; u < t; ++u) {
        if (nb[j][t] == nb[j][u]) nb[j][t] = PADSLOT;
      }
    }
  }

  // ---- init x0 = D^{-1} b ----
  if (tid < 8) { xb[0][NN + tid] = 0.f; xb[1][NN + tid] = 0.f; }
  float xc[RPT], xp[RPT], xpp[RPT];
  #pragma unroll
  for (int j = 0; j < RPT; ++j) {
    xc[j] = rinvd[j]; xp[j] = xc[j]; xpp[j] = xc[j];
    xb[0][tid + j * TPB] = xc[j];
  }
  __syncthreads();

  // ---- Jacobi + guarded Aitken rounds: 8+A, 3+A ----
  int cur = 0;
  for (int rd = 0; rd < 2; ++rd) {
    const int iters = (rd == 0) ? 8 : 3;
    for (int it = 0; it < iters; ++it) {
      float xn[RPT];
      #pragma unroll
      for (int j = 0; j < RPT; ++j) {
        float s = 0.f;
        #pragma unroll
        for (int t = 0; t < DEGN; ++t) s += xb[cur][nb[j][t]];
        xn[j] = rinvd[j] + cinvd[j] * s;
      }
      #pragma unroll
      for (int j = 0; j < RPT; ++j) xb[cur ^ 1][tid + j * TPB] = xn[j];
      __syncthreads();
      #pragma unroll
      for (int j = 0; j < RPT; ++j) { xpp[j] = xp[j]; xp[j] = xc[j]; xc[j] = xn[j]; }
      cur ^= 1;
    }

    // Aitken: x* = x_{k+1} + mu/(1-mu)*d2,  mu = <d1,d2>/<d1,d1>
    double d11 = 0.0, d12 = 0.0, dxx = 0.0;
    #pragma unroll
    for (int j = 0; j < RPT; ++j) {
      const double d1 = (double)xp[j] - (double)xpp[j];
      const double d2 = (double)xc[j] - (double)xp[j];
      d11 += d1 * d1; d12 += d1 * d2; dxx += (double)xc[j] * (double)xc[j];
    }
    d11 = wave_reduce_d(d11); d12 = wave_reduce_d(d12); dxx = wave_reduce_d(dxx);
    if (lane == 0) { red[wid] = d11; red[16 + wid] = d12; red[32 + wid] = dxx; }
    __syncthreads();
    if (tid == 0) {
      double a = 0.0, b = 0.0, x2 = 0.0;
      for (int w = 0; w < 16; ++w) { a += red[w]; b += red[16 + w]; x2 += red[32 + w]; }
      double f = 0.0;
      if (a > 1e-12 * x2) {                 // skip at fp32 quantization floor
        double mu = b / a;
        if (mu > -0.5) {                    // f >= -1/3: no sign flip possible
          if (mu > 0.9999) mu = 0.9999;     // cap amplification at 1e4
          f = mu / (1.0 - mu);
        }
      }
      red[90] = f;
    }
    __syncthreads();
    const float f = (float)red[90];
    #pragma unroll
    for (int j = 0; j < RPT; ++j) {
      xc[j] = xc[j] + f * (xc[j] - xp[j]);
      xb[cur][tid + j * TPB] = xc[j];
      xp[j] = xc[j]; xpp[j] = xc[j];
    }
    __syncthreads();
  }

  // ---- epilogue: s_b = sum_i g_i * cd[i,b] / (cd[i,:]@rho) ----
  double acc[NC] = {0, 0, 0, 0, 0};
  #pragma unroll
  for (int j = 0; j < RPT; ++j) {
    const double gs = (double)xc[j] * (double)invsr[j];
    #pragma unroll
    for (int b = 0; b < NC; ++b) acc[b] += gs * (double)cdv[j][b];
  }
  #pragma unroll
  for (int b = 0; b < NC; ++b) acc[b] = wave_reduce_d(acc[b]);
  __syncthreads();
  if (lane == 0) {
    #pragma unroll
    for (int b = 0; b < NC; ++b) red[b * 16 + wid] = acc[b];
  }
  __syncthreads();
  if (tid == 0) {
    double s[NC];
    for (int b = 0; b < NC; ++b) {
      double t = 0.0;
      for (int w = 0; w < 16; ++w) t += red[b * 16 + w];
      s[b] = t * (double)rho[b];
    }
    // I[a][b] = K*rec[a]*s[b]/N, row-major ravel
    for (int a = 0; a < NC; ++a)
      for (int b = 0; b < NC; ++b)
        wsI[blockIdx.x * 25 + a * NC + b] = (double)K * (double)rec[a] * s[b] / (double)NN;
    __threadfence();                         // drain data stores (device scope)
    __hip_atomic_store(&tok[blockIdx.x], TOK_MAGIC,
                       __ATOMIC_RELEASE, __HIP_MEMORY_SCOPE_AGENT);
  }

  // ---- block 0, wave 0: poll tokens, then compute the loss ----
  if (blockIdx.x == 0 && tid < 64) {
    for (int b = 0; b < 3; ++b) {
      while (__hip_atomic_load(&tok[b], __ATOMIC_ACQUIRE,
                               __HIP_MEMORY_SCOPE_AGENT) != TOK_MAGIC) { }
    }
    const volatile double* vI = (const volatile double*)wsI;
    double sm = 0, sd = 0, smm = 0, sdd = 0, smd = 0;
    for (int i = lane; i < 75; i += 64) {
      const double m = vI[i];
      const double d = (double)iexp[i];
      sm += m; sd += d; smm += m * m; sdd += d * d; smd += m * d;
    }
    sm = wave_reduce_d(sm); sd = wave_reduce_d(sd);
    smm = wave_reduce_d(smm); sdd = wave_reduce_d(sdd); smd = wave_reduce_d(smd);
    if (lane == 0) {
      const double n = 75.0;
      const double mm = sm / n, md = sd / n;
      const double cov = smd / n - mm * md;
      const double vm = smm / n - mm * mm;
      const double vd = sdd / n - md * md;
      out[0] = (float)(1.0 - cov / (sqrt(vm) * sqrt(vd)));
    }
  }
}

extern "C" void kernel_launch(void* const* d_in, const int* in_sizes, int n_in,
                              void* d_out, int out_size, void* d_ws, size_t ws_size,
                              hipStream_t stream) {
  const float* th1  = (const float*)d_in[0];
  const float* th2  = (const float*)d_in[1];
  const float* th3  = (const float*)d_in[2];
  const float* cd   = (const float*)d_in[3];
  const float* iexp = (const float*)d_in[4];
  const int*   nbr  = (const int*)d_in[5];

  int*    tok = (int*)d_ws;                           // 3 tokens (poisoned 0xAA)
  double* wsI = (double*)((char*)d_ws + 64);          // 75 doubles

  solve_kernel<<<3, TPB, 0, stream>>>(th1, th2, th3, cd, nbr, iexp,
                                      tok, wsI, (float*)d_out);
}

// Round 5
// 86.088 us; speedup vs baseline: 2.0217x; 1.0487x over previous
//
#include <hip/hip_runtime.h>
#include <math.h>

// loss = 1 - corr(I_model, I_exp); I_model from three 4096x4096 solves with
// A = (6c+eps_i)I - c*S, S = random 6-out adjacency (dups collapse via .set).
// Jacobi (bulk radius ~0.41, circular-law disk) + ONE guarded vector Aitken
// for the lone Perron outlier (mu ~ 1-6e-4). Whole state in LDS.
//
// Round-5 changes vs round 4 (passed, absmax 0.0, total=90.3us):
//  - sweeps 11 -> 9, Aitken rounds 2 -> 1 (9+A). Error model: Aitken bulk
//    contamination f*d2_bulk ~ 1600*0.59*0.41^9*e0_bulk ~ 0.31*e0_bulk;
//    e0_bulk/||x*|| ~ 1e-3 (Perron amp ~1600) -> shape error ~3e-4.
//    mu-hat error ~ (bulk/Perron)^2 ~ 1/820^2 -> Perron residual 2.5e-3
//    along v = pure scale of I_model = invisible to the correlation loss.
//    ~60x margin vs threshold 2.08e-2.
//  - inv_diag computed once per row (4 fp64 divides/thread instead of 8).
//  - no post-Aitken LDS write-back: epilogue works on registers.
//  - measured fixed overhead: ~64-65us of harness stream work per call
//    (268MB d_ws re-poison @85% HBM peak + input restores + graph replay),
//    invariant across rounds and outside kernel control. Kernel ~20us.

#define NN    4096
#define DEGN  6
#define NC    5
#define TPB   1024
#define RPT   4            // rows per thread: 4096/1024
#define PADSLOT NN         // dummy LDS slot (always 0) for deduped neighbours
#define XDIM (NN + 8)
#define TOK_MAGIC 0x7F3A9C51

__device__ __forceinline__ double wave_reduce_d(double v) {
  #pragma unroll
  for (int off = 32; off > 0; off >>= 1) v += __shfl_down(v, off, 64);
  return v;
}

__global__ __launch_bounds__(TPB, 1)
void solve_kernel(const float* __restrict__ th_a,
                  const float* __restrict__ th_b,
                  const float* __restrict__ th_c,
                  const float* __restrict__ cd,     // (4096,5) row-major
                  const int*   __restrict__ nbrg,   // (4096,6) row-major
                  const float* __restrict__ iexp,   // (75,)
                  int*    tok,                       // d_ws+0: 3 tokens
                  double* wsI,                       // d_ws+64: 3 x 25 doubles
                  float*  out)
{
  __shared__ float  xb[2][XDIM];
  __shared__ double red[96];

  const float* th = (blockIdx.x == 0) ? th_a : (blockIdx.x == 1) ? th_b : th_c;
  const int tid  = threadIdx.x;
  const int lane = tid & 63;
  const int wid  = tid >> 6;

  const double AREA_D = 0.8660254037844386 * 8.45e-5 * 8.45e-5;   // sqrt(3)/2*L_C^2
  const double LR_D   = 0.5773502691896258;                        // 1/sqrt(3)
  const double BS_D   = 1e12;                                      // B_SCALE/A_SCALE

  const float D   = th[0];
  const float lam = th[1];
  const float K   = th[7];
  float rho[NC], rec[NC];
  #pragma unroll
  for (int m = 0; m < NC; ++m) { rho[m] = th[2 + m]; rec[m] = th[8 + m]; }
  const float c = (float)((double)D * LR_D);

  // ---- per-row setup ----
  int   nb[RPT][DEGN];
  float rinvd[RPT], cinvd[RPT], invsr[RPT], cdv[RPT][NC];

  #pragma unroll
  for (int j = 0; j < RPT; ++j) {
    const int i = tid + j * TPB;
    float srho = 0.f, srec = 0.f;
    #pragma unroll
    for (int m = 0; m < NC; ++m) {
      const float v = cd[i * NC + m];
      cdv[j][m] = v;
      srho += v * rho[m];
      srec += v * rec[m];
    }
    const double diag = 6.0 * (double)c + AREA_D * ((double)lam + (double)K * (double)srec);
    const double inv_diag = 1.0 / diag;                        // one divide/row
    rinvd[j] = (float)(AREA_D * BS_D * (double)srho * inv_diag);
    cinvd[j] = (float)((double)c * inv_diag);
    invsr[j] = 1.0f / srho;
    #pragma unroll
    for (int t = 0; t < DEGN; ++t) nb[j][t] = nbrg[i * DEGN + t];
    // .set semantics: duplicate neighbour indices collapse to one -c entry
    #pragma unroll
    for (int t = 1; t < DEGN; ++t) {
      #pragma unroll
      for (int u = 0; u < t; ++u) {
        if (nb[j][t] == nb[j][u]) nb[j][t] = PADSLOT;
      }
    }
  }

  // ---- init x0 = D^{-1} b ----
  if (tid < 8) { xb[0][NN + tid] = 0.f; xb[1][NN + tid] = 0.f; }
  float xc[RPT], xp[RPT], xpp[RPT];
  #pragma unroll
  for (int j = 0; j < RPT; ++j) {
    xc[j] = rinvd[j]; xp[j] = xc[j]; xpp[j] = xc[j];
    xb[0][tid + j * TPB] = xc[j];
  }
  __syncthreads();

  // ---- 9 Jacobi sweeps (track last three iterates) ----
  int cur = 0;
  for (int it = 0; it < 9; ++it) {
    float xn[RPT];
    #pragma unroll
    for (int j = 0; j < RPT; ++j) {
      float s = 0.f;
      #pragma unroll
      for (int t = 0; t < DEGN; ++t) s += xb[cur][nb[j][t]];
      xn[j] = rinvd[j] + cinvd[j] * s;
    }
    #pragma unroll
    for (int j = 0; j < RPT; ++j) xb[cur ^ 1][tid + j * TPB] = xn[j];
    __syncthreads();
    #pragma unroll
    for (int j = 0; j < RPT; ++j) { xpp[j] = xp[j]; xp[j] = xc[j]; xc[j] = xn[j]; }
    cur ^= 1;
  }

  // ---- guarded Aitken: x* = x9 + mu/(1-mu)*d2,  mu = <d1,d2>/<d1,d1> ----
  double d11 = 0.0, d12 = 0.0, dxx = 0.0;
  #pragma unroll
  for (int j = 0; j < RPT; ++j) {
    const double d1 = (double)xp[j] - (double)xpp[j];
    const double d2 = (double)xc[j] - (double)xp[j];
    d11 += d1 * d1; d12 += d1 * d2; dxx += (double)xc[j] * (double)xc[j];
  }
  d11 = wave_reduce_d(d11); d12 = wave_reduce_d(d12); dxx = wave_reduce_d(dxx);
  if (lane == 0) { red[wid] = d11; red[16 + wid] = d12; red[32 + wid] = dxx; }
  __syncthreads();
  if (tid == 0) {
    double a = 0.0, b = 0.0, x2 = 0.0;
    for (int w = 0; w < 16; ++w) { a += red[w]; b += red[16 + w]; x2 += red[32 + w]; }
    double f = 0.0;
    if (a > 1e-12 * x2) {                 // skip at fp32 quantization floor
      double mu = b / a;
      if (mu > -0.5) {                    // f >= -1/3: no sign flip possible
        if (mu > 0.9999) mu = 0.9999;     // cap amplification at 1e4
        f = mu / (1.0 - mu);
      }
    }
    red[90] = f;
  }
  __syncthreads();
  const float f = (float)red[90];
  float xg[RPT];
  #pragma unroll
  for (int j = 0; j < RPT; ++j) xg[j] = xc[j] + f * (xc[j] - xp[j]);

  // ---- epilogue: s_b = sum_i g_i * cd[i,b] / (cd[i,:]@rho) ----
  __syncthreads();                         // red[] reuse
  double acc[NC] = {0, 0, 0, 0, 0};
  #pragma unroll
  for (int j = 0; j < RPT; ++j) {
    const double gs = (double)xg[j] * (double)invsr[j];
    #pragma unroll
    for (int b = 0; b < NC; ++b) acc[b] += gs * (double)cdv[j][b];
  }
  #pragma unroll
  for (int b = 0; b < NC; ++b) acc[b] = wave_reduce_d(acc[b]);
  if (lane == 0) {
    #pragma unroll
    for (int b = 0; b < NC; ++b) red[b * 16 + wid] = acc[b];
  }
  __syncthreads();
  if (tid == 0) {
    double s[NC];
    for (int b = 0; b < NC; ++b) {
      double t = 0.0;
      for (int w = 0; w < 16; ++w) t += red[b * 16 + w];
      s[b] = t * (double)rho[b];
    }
    // I[a][b] = K*rec[a]*s[b]/N, row-major ravel
    for (int a = 0; a < NC; ++a)
      for (int b = 0; b < NC; ++b)
        wsI[blockIdx.x * 25 + a * NC + b] = (double)K * (double)rec[a] * s[b] / (double)NN;
    __threadfence();                         // drain data stores (device scope)
    __hip_atomic_store(&tok[blockIdx.x], TOK_MAGIC,
                       __ATOMIC_RELEASE, __HIP_MEMORY_SCOPE_AGENT);
  }

  // ---- block 0, wave 0: poll tokens, then compute the loss ----
  if (blockIdx.x == 0 && tid < 64) {
    for (int b = 0; b < 3; ++b) {
      while (__hip_atomic_load(&tok[b], __ATOMIC_ACQUIRE,
                               __HIP_MEMORY_SCOPE_AGENT) != TOK_MAGIC) { }
    }
    const volatile double* vI = (const volatile double*)wsI;
    double sm = 0, sd = 0, smm = 0, sdd = 0, smd = 0;
    for (int i = lane; i < 75; i += 64) {
      const double m = vI[i];
      const double d = (double)iexp[i];
      sm += m; sd += d; smm += m * m; sdd += d * d; smd += m * d;
    }
    sm = wave_reduce_d(sm); sd = wave_reduce_d(sd);
    smm = wave_reduce_d(smm); sdd = wave_reduce_d(sdd); smd = wave_reduce_d(smd);
    if (lane == 0) {
      const double n = 75.0;
      const double mm = sm / n, md = sd / n;
      const double cov = smd / n - mm * md;
      const double vm = smm / n - mm * mm;
      const double vd = sdd / n - md * md;
      out[0] = (float)(1.0 - cov / (sqrt(vm) * sqrt(vd)));
    }
  }
}

extern "C" void kernel_launch(void* const* d_in, const int* in_sizes, int n_in,
                              void* d_out, int out_size, void* d_ws, size_t ws_size,
                              hipStream_t stream) {
  const float* th1  = (const float*)d_in[0];
  const float* th2  = (const float*)d_in[1];
  const float* th3  = (const float*)d_in[2];
  const float* cd   = (const float*)d_in[3];
  const float* iexp = (const float*)d_in[4];
  const int*   nbr  = (const int*)d_in[5];

  int*    tok = (int*)d_ws;                           // 3 tokens (poisoned 0xAA)
  double* wsI = (double*)((char*)d_ws + 64);          // 75 doubles

  solve_kernel<<<3, TPB, 0, stream>>>(th1, th2, th3, cd, nbr, iexp,
                                      tok, wsI, (float*)d_out);
}

// Round 6
// 82.607 us; speedup vs baseline: 2.1069x; 1.0421x over previous
//
#include <hip/hip_runtime.h>
#include <math.h>

// loss = 1 - corr(I_model, I_exp); I_model from three 4096x4096 solves with
// A = (6c+eps_i)I - c*S, S = random 6-out adjacency (dups collapse via .set).
// Jacobi (bulk radius ~0.41, circular-law disk) + ONE guarded vector Aitken
// for the lone Perron outlier (mu ~ 1-6e-4). Whole state in LDS.
//
// Round-6 changes vs round 5 (passed, absmax 0.0, total=86.1us):
//  - sweeps 9 -> 6 (6+Aitken). Evidence-based: absmax was 0.0 (<6e-8) at
//    9+A, and both error terms scale ~0.41^k -> ~1e-6 at 6+A. Independent
//    pessimistic bound: f*d2_bulk ~ 1600*0.59*0.41^6*1e-3 ~ 4.4e-3, still
//    5x under the 2.08e-2 threshold. (b = cd@rho is nearly parallel to the
//    Perron vector, so the true bulk error is ~3 orders below the generic
//    model -- measured rounds 1-5 all absmax 0.0.)
//  - final sweep keeps result in registers only (no LDS write-back+barrier);
//    Aitken and epilogue never re-read x from LDS.
//  - neighbour rows loaded as int2 x3 (24B rows, 8B-aligned).
//  - fixed ~65us/call of harness stream work (268MB d_ws re-poison @85% HBM
//    peak + input restores + graph replay) is outside kernel control.

#define NN    4096
#define DEGN  6
#define NC    5
#define TPB   1024
#define RPT   4            // rows per thread: 4096/1024
#define PADSLOT NN         // dummy LDS slot (always 0) for deduped neighbours
#define XDIM (NN + 8)
#define TOK_MAGIC 0x7F3A9C51

__device__ __forceinline__ double wave_reduce_d(double v) {
  #pragma unroll
  for (int off = 32; off > 0; off >>= 1) v += __shfl_down(v, off, 64);
  return v;
}

__global__ __launch_bounds__(TPB, 1)
void solve_kernel(const float* __restrict__ th_a,
                  const float* __restrict__ th_b,
                  const float* __restrict__ th_c,
                  const float* __restrict__ cd,     // (4096,5) row-major
                  const int*   __restrict__ nbrg,   // (4096,6) row-major
                  const float* __restrict__ iexp,   // (75,)
                  int*    tok,                       // d_ws+0: 3 tokens
                  double* wsI,                       // d_ws+64: 3 x 25 doubles
                  float*  out)
{
  __shared__ float  xb[2][XDIM];
  __shared__ double red[96];

  const float* th = (blockIdx.x == 0) ? th_a : (blockIdx.x == 1) ? th_b : th_c;
  const int tid  = threadIdx.x;
  const int lane = tid & 63;
  const int wid  = tid >> 6;

  const double AREA_D = 0.8660254037844386 * 8.45e-5 * 8.45e-5;   // sqrt(3)/2*L_C^2
  const double LR_D   = 0.5773502691896258;                        // 1/sqrt(3)
  const double BS_D   = 1e12;                                      // B_SCALE/A_SCALE

  const float D   = th[0];
  const float lam = th[1];
  const float K   = th[7];
  float rho[NC], rec[NC];
  #pragma unroll
  for (int m = 0; m < NC; ++m) { rho[m] = th[2 + m]; rec[m] = th[8 + m]; }
  const float c = (float)((double)D * LR_D);

  // ---- per-row setup ----
  int   nb[RPT][DEGN];
  float rinvd[RPT], cinvd[RPT], invsr[RPT], cdv[RPT][NC];

  #pragma unroll
  for (int j = 0; j < RPT; ++j) {
    const int i = tid + j * TPB;
    float srho = 0.f, srec = 0.f;
    #pragma unroll
    for (int m = 0; m < NC; ++m) {
      const float v = cd[i * NC + m];
      cdv[j][m] = v;
      srho += v * rho[m];
      srec += v * rec[m];
    }
    const double diag = 6.0 * (double)c + AREA_D * ((double)lam + (double)K * (double)srec);
    const double inv_diag = 1.0 / diag;                        // one divide/row
    rinvd[j] = (float)(AREA_D * BS_D * (double)srho * inv_diag);
    cinvd[j] = (float)((double)c * inv_diag);
    invsr[j] = 1.0f / srho;
    // neighbour row: 6 ints = 24B, 8B-aligned -> three int2 loads
    const int2* np2 = (const int2*)(nbrg + (size_t)i * DEGN);
    const int2 n01 = np2[0], n23 = np2[1], n45 = np2[2];
    nb[j][0] = n01.x; nb[j][1] = n01.y;
    nb[j][2] = n23.x; nb[j][3] = n23.y;
    nb[j][4] = n45.x; nb[j][5] = n45.y;
    // .set semantics: duplicate neighbour indices collapse to one -c entry
    #pragma unroll
    for (int t = 1; t < DEGN; ++t) {
      #pragma unroll
      for (int u = 0; u < t; ++u) {
        if (nb[j][t] == nb[j][u]) nb[j][t] = PADSLOT;
      }
    }
  }

  // ---- init x0 = D^{-1} b ----
  if (tid < 8) { xb[0][NN + tid] = 0.f; xb[1][NN + tid] = 0.f; }
  float xc[RPT], xp[RPT], xpp[RPT];
  #pragma unroll
  for (int j = 0; j < RPT; ++j) {
    xc[j] = rinvd[j]; xp[j] = xc[j]; xpp[j] = xc[j];
    xb[0][tid + j * TPB] = xc[j];
  }
  __syncthreads();

  // ---- 5 Jacobi sweeps with LDS write-back ----
  int cur = 0;
  for (int it = 0; it < 5; ++it) {
    float xn[RPT];
    #pragma unroll
    for (int j = 0; j < RPT; ++j) {
      float s = 0.f;
      #pragma unroll
      for (int t = 0; t < DEGN; ++t) s += xb[cur][nb[j][t]];
      xn[j] = rinvd[j] + cinvd[j] * s;
    }
    #pragma unroll
    for (int j = 0; j < RPT; ++j) xb[cur ^ 1][tid + j * TPB] = xn[j];
    __syncthreads();
    #pragma unroll
    for (int j = 0; j < RPT; ++j) { xpp[j] = xp[j]; xp[j] = xc[j]; xc[j] = xn[j]; }
    cur ^= 1;
  }

  // ---- sweep 6: registers only (nothing re-reads x from LDS after this) ----
  {
    float xn[RPT];
    #pragma unroll
    for (int j = 0; j < RPT; ++j) {
      float s = 0.f;
      #pragma unroll
      for (int t = 0; t < DEGN; ++t) s += xb[cur][nb[j][t]];
      xn[j] = rinvd[j] + cinvd[j] * s;
    }
    #pragma unroll
    for (int j = 0; j < RPT; ++j) { xpp[j] = xp[j]; xp[j] = xc[j]; xc[j] = xn[j]; }
  }

  // ---- guarded Aitken: x* = x6 + mu/(1-mu)*d2,  mu = <d1,d2>/<d1,d1> ----
  double d11 = 0.0, d12 = 0.0, dxx = 0.0;
  #pragma unroll
  for (int j = 0; j < RPT; ++j) {
    const double d1 = (double)xp[j] - (double)xpp[j];
    const double d2 = (double)xc[j] - (double)xp[j];
    d11 += d1 * d1; d12 += d1 * d2; dxx += (double)xc[j] * (double)xc[j];
  }
  d11 = wave_reduce_d(d11); d12 = wave_reduce_d(d12); dxx = wave_reduce_d(dxx);
  if (lane == 0) { red[wid] = d11; red[16 + wid] = d12; red[32 + wid] = dxx; }
  __syncthreads();
  if (tid == 0) {
    double a = 0.0, b = 0.0, x2 = 0.0;
    for (int w = 0; w < 16; ++w) { a += red[w]; b += red[16 + w]; x2 += red[32 + w]; }
    double f = 0.0;
    if (a > 1e-12 * x2) {                 // skip at fp32 quantization floor
      double mu = b / a;
      if (mu > -0.5) {                    // f >= -1/3: no sign flip possible
        if (mu > 0.9999) mu = 0.9999;     // cap amplification at 1e4
        f = mu / (1.0 - mu);
      }
    }
    red[90] = f;
  }
  __syncthreads();
  const float f = (float)red[90];
  float xg[RPT];
  #pragma unroll
  for (int j = 0; j < RPT; ++j) xg[j] = xc[j] + f * (xc[j] - xp[j]);

  // ---- epilogue: s_b = sum_i g_i * cd[i,b] / (cd[i,:]@rho) ----
  __syncthreads();                         // red[] reuse
  double acc[NC] = {0, 0, 0, 0, 0};
  #pragma unroll
  for (int j = 0; j < RPT; ++j) {
    const double gs = (double)xg[j] * (double)invsr[j];
    #pragma unroll
    for (int b = 0; b < NC; ++b) acc[b] += gs * (double)cdv[j][b];
  }
  #pragma unroll
  for (int b = 0; b < NC; ++b) acc[b] = wave_reduce_d(acc[b]);
  if (lane == 0) {
    #pragma unroll
    for (int b = 0; b < NC; ++b) red[b * 16 + wid] = acc[b];
  }
  __syncthreads();
  if (tid == 0) {
    double s[NC];
    for (int b = 0; b < NC; ++b) {
      double t = 0.0;
      for (int w = 0; w < 16; ++w) t += red[b * 16 + w];
      s[b] = t * (double)rho[b];
    }
    // I[a][b] = K*rec[a]*s[b]/N, row-major ravel
    for (int a = 0; a < NC; ++a)
      for (int b = 0; b < NC; ++b)
        wsI[blockIdx.x * 25 + a * NC + b] = (double)K * (double)rec[a] * s[b] / (double)NN;
    __threadfence();                         // drain data stores (device scope)
    __hip_atomic_store(&tok[blockIdx.x], TOK_MAGIC,
                       __ATOMIC_RELEASE, __HIP_MEMORY_SCOPE_AGENT);
  }

  // ---- block 0, wave 0: poll tokens, then compute the loss ----
  if (blockIdx.x == 0 && tid < 64) {
    for (int b = 0; b < 3; ++b) {
      while (__hip_atomic_load(&tok[b], __ATOMIC_ACQUIRE,
                               __HIP_MEMORY_SCOPE_AGENT) != TOK_MAGIC) { }
    }
    const volatile double* vI = (const volatile double*)wsI;
    double sm = 0, sd = 0, smm = 0, sdd = 0, smd = 0;
    for (int i = lane; i < 75; i += 64) {
      const double m = vI[i];
      const double d = (double)iexp[i];
      sm += m; sd += d; smm += m * m; sdd += d * d; smd += m * d;
    }
    sm = wave_reduce_d(sm); sd = wave_reduce_d(sd);
    smm = wave_reduce_d(smm); sdd = wave_reduce_d(sdd); smd = wave_reduce_d(smd);
    if (lane == 0) {
      const double n = 75.0;
      const double mm = sm / n, md = sd / n;
      const double cov = smd / n - mm * md;
      const double vm = smm / n - mm * mm;
      const double vd = sdd / n - md * md;
      out[0] = (float)(1.0 - cov / (sqrt(vm) * sqrt(vd)));
    }
  }
}

extern "C" void kernel_launch(void* const* d_in, const int* in_sizes, int n_in,
                              void* d_out, int out_size, void* d_ws, size_t ws_size,
                              hipStream_t stream) {
  const float* th1  = (const float*)d_in[0];
  const float* th2  = (const float*)d_in[1];
  const float* th3  = (const float*)d_in[2];
  const float* cd   = (const float*)d_in[3];
  const float* iexp = (const float*)d_in[4];
  const int*   nbr  = (const int*)d_in[5];

  int*    tok = (int*)d_ws;                           // 3 tokens (poisoned 0xAA)
  double* wsI = (double*)((char*)d_ws + 64);          // 75 doubles

  solve_kernel<<<3, TPB, 0, stream>>>(th1, th2, th3, cd, nbr, iexp,
                                      tok, wsI, (float*)d_out);
}

// Round 7
// 77.715 us; speedup vs baseline: 2.2396x; 1.0629x over previous
//
#include <hip/hip_runtime.h>
#include <math.h>

// loss = 1 - corr(I_model, I_exp); I_model from three 4096x4096 solves with
// A = (6c+eps_i)I - c*S, S = random 6-out adjacency (dups collapse via .set).
// Jacobi (bulk radius ~0.41, circular-law disk) + ONE guarded vector Aitken
// for the lone Perron outlier (mu ~ 1-6e-4). Whole state in LDS.
//
// Round-7 changes vs round 6 (passed, absmax 0.0, total=82.6us):
//  - sweeps 6 -> 4 (3 LDS sweeps + 1 register-only sweep + Aitken). Measured
//    error at 6+A was < 6e-8 (absmax 0.0, as at 9+A/11+A/16+A); both error
//    channels scale <= 36x going to 4+A -> ~2e-6, four orders under the
//    2.08e-2 threshold. mu-hat stays far from the clamp (extrapolated
//    delta-mu ~ 3.5e-6 << 1-mu = 6e-4). 4 is the floor for this scheme:
//    Aitken needs x2,x3,x4 (two diffs); at 3+A the first diff sits at k=2
//    where bulk:Perron in d is only ~4 -> mu-hat bias ~6%, genuinely risky.
//  - NOTE (model correction): per-solve Perron error is NOT loss-invisible
//    (correlation is over the concatenated 75-vector, so per-theta scale is
//    shape). The real reason the aggressive schedule works: bulk terms in
//    the Aitken dot products cancel incoherently over 4096 entries, so
//    mu-hat is ~n times more accurate than the naive (bulk/Perron)^2 bound.
//  - fixed ~65us/call of harness stream work (268MB d_ws re-poison @85% HBM
//    peak + input restores + graph replay) is outside kernel control;
//    kernel is ~14us of the ~79us total.

#define NN    4096
#define DEGN  6
#define NC    5
#define TPB   1024
#define RPT   4            // rows per thread: 4096/1024
#define PADSLOT NN         // dummy LDS slot (always 0) for deduped neighbours
#define XDIM (NN + 8)
#define TOK_MAGIC 0x7F3A9C51

__device__ __forceinline__ double wave_reduce_d(double v) {
  #pragma unroll
  for (int off = 32; off > 0; off >>= 1) v += __shfl_down(v, off, 64);
  return v;
}

__global__ __launch_bounds__(TPB, 1)
void solve_kernel(const float* __restrict__ th_a,
                  const float* __restrict__ th_b,
                  const float* __restrict__ th_c,
                  const float* __restrict__ cd,     // (4096,5) row-major
                  const int*   __restrict__ nbrg,   // (4096,6) row-major
                  const float* __restrict__ iexp,   // (75,)
                  int*    tok,                       // d_ws+0: 3 tokens
                  double* wsI,                       // d_ws+64: 3 x 25 doubles
                  float*  out)
{
  __shared__ float  xb[2][XDIM];
  __shared__ double red[96];

  const float* th = (blockIdx.x == 0) ? th_a : (blockIdx.x == 1) ? th_b : th_c;
  const int tid  = threadIdx.x;
  const int lane = tid & 63;
  const int wid  = tid >> 6;

  const double AREA_D = 0.8660254037844386 * 8.45e-5 * 8.45e-5;   // sqrt(3)/2*L_C^2
  const double LR_D   = 0.5773502691896258;                        // 1/sqrt(3)
  const double BS_D   = 1e12;                                      // B_SCALE/A_SCALE

  const float D   = th[0];
  const float lam = th[1];
  const float K   = th[7];
  float rho[NC], rec[NC];
  #pragma unroll
  for (int m = 0; m < NC; ++m) { rho[m] = th[2 + m]; rec[m] = th[8 + m]; }
  const float c = (float)((double)D * LR_D);

  // ---- per-row setup ----
  int   nb[RPT][DEGN];
  float rinvd[RPT], cinvd[RPT], invsr[RPT], cdv[RPT][NC];

  #pragma unroll
  for (int j = 0; j < RPT; ++j) {
    const int i = tid + j * TPB;
    float srho = 0.f, srec = 0.f;
    #pragma unroll
    for (int m = 0; m < NC; ++m) {
      const float v = cd[i * NC + m];
      cdv[j][m] = v;
      srho += v * rho[m];
      srec += v * rec[m];
    }
    const double diag = 6.0 * (double)c + AREA_D * ((double)lam + (double)K * (double)srec);
    const double inv_diag = 1.0 / diag;                        // one divide/row
    rinvd[j] = (float)(AREA_D * BS_D * (double)srho * inv_diag);
    cinvd[j] = (float)((double)c * inv_diag);
    invsr[j] = 1.0f / srho;
    // neighbour row: 6 ints = 24B, 8B-aligned -> three int2 loads
    const int2* np2 = (const int2*)(nbrg + (size_t)i * DEGN);
    const int2 n01 = np2[0], n23 = np2[1], n45 = np2[2];
    nb[j][0] = n01.x; nb[j][1] = n01.y;
    nb[j][2] = n23.x; nb[j][3] = n23.y;
    nb[j][4] = n45.x; nb[j][5] = n45.y;
    // .set semantics: duplicate neighbour indices collapse to one -c entry
    #pragma unroll
    for (int t = 1; t < DEGN; ++t) {
      #pragma unroll
      for (int u = 0; u < t; ++u) {
        if (nb[j][t] == nb[j][u]) nb[j][t] = PADSLOT;
      }
    }
  }

  // ---- init x0 = D^{-1} b ----
  if (tid < 8) { xb[0][NN + tid] = 0.f; xb[1][NN + tid] = 0.f; }
  float xc[RPT], xp[RPT], xpp[RPT];
  #pragma unroll
  for (int j = 0; j < RPT; ++j) {
    xc[j] = rinvd[j]; xp[j] = xc[j]; xpp[j] = xc[j];
    xb[0][tid + j * TPB] = xc[j];
  }
  __syncthreads();

  // ---- 3 Jacobi sweeps with LDS write-back ----
  int cur = 0;
  for (int it = 0; it < 3; ++it) {
    float xn[RPT];
    #pragma unroll
    for (int j = 0; j < RPT; ++j) {
      float s = 0.f;
      #pragma unroll
      for (int t = 0; t < DEGN; ++t) s += xb[cur][nb[j][t]];
      xn[j] = rinvd[j] + cinvd[j] * s;
    }
    #pragma unroll
    for (int j = 0; j < RPT; ++j) xb[cur ^ 1][tid + j * TPB] = xn[j];
    __syncthreads();
    #pragma unroll
    for (int j = 0; j < RPT; ++j) { xpp[j] = xp[j]; xp[j] = xc[j]; xc[j] = xn[j]; }
    cur ^= 1;
  }

  // ---- sweep 4: registers only (nothing re-reads x from LDS after this) ----
  {
    float xn[RPT];
    #pragma unroll
    for (int j = 0; j < RPT; ++j) {
      float s = 0.f;
      #pragma unroll
      for (int t = 0; t < DEGN; ++t) s += xb[cur][nb[j][t]];
      xn[j] = rinvd[j] + cinvd[j] * s;
    }
    #pragma unroll
    for (int j = 0; j < RPT; ++j) { xpp[j] = xp[j]; xp[j] = xc[j]; xc[j] = xn[j]; }
  }

  // ---- guarded Aitken: x* = x4 + mu/(1-mu)*d2,  mu = <d1,d2>/<d1,d1> ----
  double d11 = 0.0, d12 = 0.0, dxx = 0.0;
  #pragma unroll
  for (int j = 0; j < RPT; ++j) {
    const double d1 = (double)xp[j] - (double)xpp[j];
    const double d2 = (double)xc[j] - (double)xp[j];
    d11 += d1 * d1; d12 += d1 * d2; dxx += (double)xc[j] * (double)xc[j];
  }
  d11 = wave_reduce_d(d11); d12 = wave_reduce_d(d12); dxx = wave_reduce_d(dxx);
  if (lane == 0) { red[wid] = d11; red[16 + wid] = d12; red[32 + wid] = dxx; }
  __syncthreads();
  if (tid == 0) {
    double a = 0.0, b = 0.0, x2 = 0.0;
    for (int w = 0; w < 16; ++w) { a += red[w]; b += red[16 + w]; x2 += red[32 + w]; }
    double f = 0.0;
    if (a > 1e-12 * x2) {                 // skip at fp32 quantization floor
      double mu = b / a;
      if (mu > -0.5) {                    // f >= -1/3: no sign flip possible
        if (mu > 0.9999) mu = 0.9999;     // cap amplification at 1e4
        f = mu / (1.0 - mu);
      }
    }
    red[90] = f;
  }
  __syncthreads();
  const float f = (float)red[90];
  float xg[RPT];
  #pragma unroll
  for (int j = 0; j < RPT; ++j) xg[j] = xc[j] + f * (xc[j] - xp[j]);

  // ---- epilogue: s_b = sum_i g_i * cd[i,b] / (cd[i,:]@rho) ----
  __syncthreads();                         // red[] reuse
  double acc[NC] = {0, 0, 0, 0, 0};
  #pragma unroll
  for (int j = 0; j < RPT; ++j) {
    const double gs = (double)xg[j] * (double)invsr[j];
    #pragma unroll
    for (int b = 0; b < NC; ++b) acc[b] += gs * (double)cdv[j][b];
  }
  #pragma unroll
  for (int b = 0; b < NC; ++b) acc[b] = wave_reduce_d(acc[b]);
  if (lane == 0) {
    #pragma unroll
    for (int b = 0; b < NC; ++b) red[b * 16 + wid] = acc[b];
  }
  __syncthreads();
  if (tid == 0) {
    double s[NC];
    for (int b = 0; b < NC; ++b) {
      double t = 0.0;
      for (int w = 0; w < 16; ++w) t += red[b * 16 + w];
      s[b] = t * (double)rho[b];
    }
    // I[a][b] = K*rec[a]*s[b]/N, row-major ravel
    for (int a = 0; a < NC; ++a)
      for (int b = 0; b < NC; ++b)
        wsI[blockIdx.x * 25 + a * NC + b] = (double)K * (double)rec[a] * s[b] / (double)NN;
    __threadfence();                         // drain data stores (device scope)
    __hip_atomic_store(&tok[blockIdx.x], TOK_MAGIC,
                       __ATOMIC_RELEASE, __HIP_MEMORY_SCOPE_AGENT);
  }

  // ---- block 0, wave 0: poll tokens, then compute the loss ----
  if (blockIdx.x == 0 && tid < 64) {
    for (int b = 0; b < 3; ++b) {
      while (__hip_atomic_load(&tok[b], __ATOMIC_ACQUIRE,
                               __HIP_MEMORY_SCOPE_AGENT) != TOK_MAGIC) { }
    }
    const volatile double* vI = (const volatile double*)wsI;
    double sm = 0, sd = 0, smm = 0, sdd = 0, smd = 0;
    for (int i = lane; i < 75; i += 64) {
      const double m = vI[i];
      const double d = (double)iexp[i];
      sm += m; sd += d; smm += m * m; sdd += d * d; smd += m * d;
    }
    sm = wave_reduce_d(sm); sd = wave_reduce_d(sd);
    smm = wave_reduce_d(smm); sdd = wave_reduce_d(sdd); smd = wave_reduce_d(smd);
    if (lane == 0) {
      const double n = 75.0;
      const double mm = sm / n, md = sd / n;
      const double cov = smd / n - mm * md;
      const double vm = smm / n - mm * mm;
      const double vd = sdd / n - md * md;
      out[0] = (float)(1.0 - cov / (sqrt(vm) * sqrt(vd)));
    }
  }
}

extern "C" void kernel_launch(void* const* d_in, const int* in_sizes, int n_in,
                              void* d_out, int out_size, void* d_ws, size_t ws_size,
                              hipStream_t stream) {
  const float* th1  = (const float*)d_in[0];
  const float* th2  = (const float*)d_in[1];
  const float* th3  = (const float*)d_in[2];
  const float* cd   = (const float*)d_in[3];
  const float* iexp = (const float*)d_in[4];
  const int*   nbr  = (const int*)d_in[5];

  int*    tok = (int*)d_ws;                           // 3 tokens (poisoned 0xAA)
  double* wsI = (double*)((char*)d_ws + 64);          // 75 doubles

  solve_kernel<<<3, TPB, 0, stream>>>(th1, th2, th3, cd, nbr, iexp,
                                      tok, wsI, (float*)d_out);
}